// Round 13
// baseline (791.415 us; speedup 1.0000x reference)
//
#include <hip/hip_runtime.h>
#include <hip/hip_fp16.h>

typedef __attribute__((ext_vector_type(8))) _Float16 half8;
typedef __attribute__((ext_vector_type(4))) _Float16 half4;
typedef __attribute__((ext_vector_type(4))) float float4v;

#define NPIX 16384  // 128*128

__device__ inline half8 h8zero() {
    half8 z = {(_Float16)0, (_Float16)0, (_Float16)0, (_Float16)0,
               (_Float16)0, (_Float16)0, (_Float16)0, (_Float16)0};
    return z;
}

// ---------------- all weight packing + head conv in ONE dispatch ----------------
__global__ void pack_all(const float* __restrict__ rb_w, const float* __restrict__ tail_w,
                         const float* __restrict__ mw0, const float* __restrict__ mw1,
                         const float* __restrict__ mw2, const float* __restrict__ mw3,
                         const float* __restrict__ mw4, const float* __restrict__ mb0,
                         const float* __restrict__ x, const float* __restrict__ head_w,
                         const float* __restrict__ head_b,
                         _Float16* __restrict__ pwc, _Float16* __restrict__ pw0,
                         _Float16* __restrict__ pwm, float* __restrict__ b0p,
                         _Float16* __restrict__ h0) {
    int idx = blockIdx.x * 256 + threadIdx.x;
    if (idx < 1216512) {                      // conv weights -> B-frag order
        int ci = idx / 36864;
        int e  = idx % 36864;
        int j = e & 7, ln = (e >> 3) & 63, kcnt = e >> 9;
        int kc = kcnt % 18, ntc = kcnt / 18;
        int k = kc * 32 + (ln >> 4) * 8 + j;
        int nn = ntc * 16 + (ln & 15);
        int ij = k >> 6, c = k & 63;
        const float* src = (ci < 32) ? (rb_w + ci * 36864) : tail_w;
        pwc[idx] = (_Float16)src[(nn * 64 + c) * 9 + ij];
        return;
    }
    idx -= 1216512;
    if (idx < 147456) {                       // mw0[:576] pack (N=256)
        int j = idx & 7, ln = (idx >> 3) & 63, kcnt = idx >> 9;
        int kc = kcnt % 18, ntc = kcnt / 18;
        int k = kc * 32 + (ln >> 4) * 8 + j;
        int nn = ntc * 16 + (ln & 15);
        int ij = k >> 6, c = k & 63;
        pw0[idx] = (_Float16)mw0[(c * 9 + ij) * 256 + nn];
        return;
    }
    idx -= 147456;
    if (idx < 200704) {                       // mlp hidden + padded mw4
        if (idx < 196608) {
            int l = idx / 65536;
            int e = idx % 65536;
            int j = e & 7, ln = (e >> 3) & 63, kcnt = e >> 9;
            int kc = kcnt & 7, ntc = kcnt >> 3;
            int k = kc * 32 + (ln >> 4) * 8 + j;
            int nn = ntc * 16 + (ln & 15);
            const float* w = (l == 0) ? mw1 : ((l == 1) ? mw2 : mw3);
            pwm[idx] = (_Float16)w[k * 256 + nn];
        } else {
            int e = idx - 196608;
            int j = e & 7, ln = (e >> 3) & 63, kc = e >> 9;
            int k = kc * 32 + (ln >> 4) * 8 + j;
            int nn = ln & 15;
            pwm[idx] = (nn < 3) ? (_Float16)mw4[k * 3 + nn] : (_Float16)0.0f;
        }
        return;
    }
    idx -= 200704;
    if (idx < 256) {
        b0p[idx] = mb0[idx] + 0.5f * (mw0[578 * 256 + idx] + mw0[579 * 256 + idx]);
        return;
    }
    idx -= 256;
    if (idx < NPIX * 64) {                    // head conv (Cin=3, direct fp32)
        int o = idx & 63, p = idx >> 6;
        int py = p >> 7, px = p & 127;
        float acc = head_b[o];
        #pragma unroll
        for (int c = 0; c < 3; ++c)
            #pragma unroll
            for (int i = 0; i < 3; ++i)
                #pragma unroll
                for (int jj = 0; jj < 3; ++jj) {
                    int y = py + i - 1, xx = px + jj - 1;
                    if (y >= 0 && y < 128 && xx >= 0 && xx < 128)
                        acc += x[c * 16384 + y * 128 + xx]
                             * head_w[((o * 3 + c) * 3 + i) * 3 + jj];
                }
        h0[idx] = (_Float16)acc;
    }
}

// ---------------- fused 4-resblock kernel (rb_quad) ----------------
// Grid 256 = 16x16 tiles of 8x8 output px. Halo 8. 512 thr = 8 waves:
// nt = wave&3 (16 couts), mhalf = wave>>2 (interleaved m-tile split).
// LDS: IN 24x24 px (83 KB) + MID up to 22x22 px (70 KB) = 153 KB (<160 KB/CU).
// Conv k (1..8) outputs (24-2k)^2 at halo 8-k; even convs add residual in-place
// into IN at offset ROFF=k; OOB positions forced to 0 == zero-pad semantics.
#define LDS_STRIDE 72

template <int S, int SW, int SOFF, int RES, int ROFF>
__device__ __forceinline__ void qconv_stage(
    const _Float16* __restrict__ src, _Float16* __restrict__ dst,
    _Float16* __restrict__ INb,
    const _Float16* __restrict__ pw, const float* __restrict__ bias,
    int q, int r, int nt, int mhalf, int gy0, int gx0, _Float16* __restrict__ gout)
{
    half8 B[18];
    #pragma unroll
    for (int kc = 0; kc < 18; ++kc)
        B[kc] = *(const half8*)(pw + (((nt * 18 + kc) * 64 + (q << 4) + r) << 3));
    int nb = nt << 4;
    float bv = bias[nb + r];
    constexpr int NPXc = S * S;
    constexpr int NT = (NPXc + 15) >> 4;
    #pragma unroll 1
    for (int tl = mhalf; tl < NT; tl += 2) {
        int pa = tl * 16 + r;
        int ca = pa < NPXc ? pa : NPXc - 1;
        int my = ca / S, mx = ca % S;
        float4v acc = {0.f, 0.f, 0.f, 0.f};
        #pragma unroll
        for (int kc = 0; kc < 18; ++kc) {
            int ij = kc >> 1;
            int di = ij / 3 - 1;
            int dj = ij % 3 - 1;
            int cb = ((kc & 1) << 5) + (q << 3);
            int sp = (my + 1 + di + SOFF) * SW + (mx + 1 + dj + SOFF);
            half8 a = *(const half8*)(src + sp * LDS_STRIDE + cb);
            acc = __builtin_amdgcn_mfma_f32_16x16x32_f16(a, B[kc], acc, 0, 0, 0);
        }
        #pragma unroll
        for (int reg = 0; reg < 4; ++reg) {
            int pc = tl * 16 + (q << 2) + reg;
            if (pc >= NPXc) continue;
            int dy = pc / S, dx = pc % S;
            int gy = gy0 + dy, gx = gx0 + dx;
            bool valid = (gy >= 0 && gy < 128 && gx >= 0 && gx < 128);
            if (RES == 0) {
                float v = fmaxf(acc[reg] + bv, 0.f);
                dst[pc * LDS_STRIDE + nb + r] = valid ? (_Float16)v : (_Float16)0.0f;
            } else if (RES == 1) {
                int sl = ((dy + ROFF) * 24 + dx + ROFF) * LDS_STRIDE + nb + r;
                float v = acc[reg] + bv + (float)INb[sl];
                INb[sl] = valid ? (_Float16)v : (_Float16)0.0f;
            } else {
                int sl = ((dy + ROFF) * 24 + dx + ROFF) * LDS_STRIDE + nb + r;
                float v = acc[reg] + bv + (float)INb[sl];
                gout[(((gy << 7) + gx) << 6) + nb + r] = (_Float16)v;
            }
        }
    }
}

__global__ __launch_bounds__(512, 1)
void rb_quad(const _Float16* __restrict__ img, const _Float16* __restrict__ pw,
             const float* __restrict__ bias, _Float16* __restrict__ out) {
    __shared__ _Float16 IN[576 * LDS_STRIDE];    // 24x24 px, 83 KB
    __shared__ _Float16 MID[484 * LDS_STRIDE];   // up to 22x22 px, 70 KB
    int t = threadIdx.x;
    int wave = t >> 6, lane = t & 63, q = lane >> 4, r = lane & 15;
    int nt = wave & 3, mhalf = wave >> 2;
    int tr = blockIdx.x >> 4, tc = blockIdx.x & 15;
    int ty0 = tr << 3, tx0 = tc << 3;

    // stage IN (halo 8): global rows ty0-8..ty0+15, cols tx0-8..tx0+15
    #pragma unroll
    for (int i = 0; i < 9; ++i) {
        int idx = t + i * 512;                   // 4608 = 576 px * 8 chunks
        int px = idx >> 3, c = idx & 7;
        int iy = px / 24, ix = px % 24;
        int gy = ty0 - 8 + iy, gx = tx0 - 8 + ix;
        half8 v = h8zero();
        if (gy >= 0 && gy < 128 && gx >= 0 && gx < 128)
            v = *(const half8*)(img + (((gy << 7) + gx) << 6) + (c << 3));
        *(half8*)(IN + px * LDS_STRIDE + (c << 3)) = v;
    }
    __syncthreads();

    qconv_stage<22, 24, 0, 0, 0>(IN, MID, IN, pw, bias, q, r, nt, mhalf,
                                 ty0 - 7, tx0 - 7, nullptr);
    __syncthreads();
    qconv_stage<20, 22, 0, 1, 2>(MID, MID, IN, pw + 36864, bias + 64, q, r, nt, mhalf,
                                 ty0 - 6, tx0 - 6, nullptr);
    __syncthreads();
    qconv_stage<18, 24, 2, 0, 0>(IN, MID, IN, pw + 2 * 36864, bias + 128, q, r, nt, mhalf,
                                 ty0 - 5, tx0 - 5, nullptr);
    __syncthreads();
    qconv_stage<16, 18, 0, 1, 4>(MID, MID, IN, pw + 3 * 36864, bias + 192, q, r, nt, mhalf,
                                 ty0 - 4, tx0 - 4, nullptr);
    __syncthreads();
    qconv_stage<14, 24, 4, 0, 0>(IN, MID, IN, pw + 4 * 36864, bias + 256, q, r, nt, mhalf,
                                 ty0 - 3, tx0 - 3, nullptr);
    __syncthreads();
    qconv_stage<12, 14, 0, 1, 6>(MID, MID, IN, pw + 5 * 36864, bias + 320, q, r, nt, mhalf,
                                 ty0 - 2, tx0 - 2, nullptr);
    __syncthreads();
    qconv_stage<10, 24, 6, 0, 0>(IN, MID, IN, pw + 6 * 36864, bias + 384, q, r, nt, mhalf,
                                 ty0 - 1, tx0 - 1, nullptr);
    __syncthreads();
    qconv_stage<8, 10, 0, 2, 8>(MID, MID, IN, pw + 7 * 36864, bias + 448, q, r, nt, mhalf,
                                ty0, tx0, out);
}

// ---------------- unfused conv (tail + stage-A) ----------
template <int NTOT, int MTPER, bool RELU, bool RES, bool F32OUT>
__global__ __launch_bounds__(256, 2)
void conv_mfma_r(const _Float16* __restrict__ img, const _Float16* __restrict__ pw,
                 const float* __restrict__ bias, const _Float16* res,
                 _Float16* outh, float* outf) {
    int wave = threadIdx.x >> 6, lane = threadIdx.x & 63;
    int q = lane >> 4, r = lane & 15;
    int nt, mt0;
    if constexpr (NTOT == 4) {
        nt = wave;
        mt0 = blockIdx.x * MTPER;
    } else {
        nt = (blockIdx.x & 3) * 4 + wave;
        mt0 = (blockIdx.x >> 2) * MTPER;
    }
    half8 B[18];
    #pragma unroll
    for (int kc = 0; kc < 18; ++kc)
        B[kc] = *(const half8*)(pw + (((nt * 18 + kc) * 64 + lane) << 3));
    int n = nt * 16 + r;
    float bv = bias[n];
    #pragma unroll
    for (int mi = 0; mi < MTPER; ++mi) {
        int mt = mt0 + mi;
        int p0 = mt * 16;
        int py = p0 >> 7;
        int pxl = (p0 & 127) + r;
        float4v acc = {0.f, 0.f, 0.f, 0.f};
        #pragma unroll
        for (int kc = 0; kc < 18; ++kc) {
            int ij = kc >> 1;
            int di = ij / 3 - 1;
            int dj = ij % 3 - 1;
            int cb = ((kc & 1) << 5) + (q << 3);
            int yy = py + di, xx = pxl + dj;
            half8 a = h8zero();
            if (yy >= 0 && yy < 128 && xx >= 0 && xx < 128)
                a = *(const half8*)(img + (((yy << 7) + xx) << 6) + cb);
            acc = __builtin_amdgcn_mfma_f32_16x16x32_f16(a, B[kc], acc, 0, 0, 0);
        }
        #pragma unroll
        for (int reg = 0; reg < 4; ++reg) {
            int p = p0 + (q << 2) + reg;
            float v = acc[reg] + bv;
            if (RES) v += (float)res[p * (NTOT * 16) + n];
            if (RELU) v = fmaxf(v, 0.f);
            if (F32OUT) outf[p * (NTOT * 16) + n] = v;
            else        outh[p * (NTOT * 16) + n] = (_Float16)v;
        }
    }
}

// ---------------- fused LIIF MLP + ensembling (32 px, 8-wave transposed) --------
// Block: 512 thr (8 waves) = 32 output pixels = 128 samples. (R12, 432 us)
__global__ __launch_bounds__(512, 4)
void mlp_kernel(const float* __restrict__ apre, const float* __restrict__ mw0,
                const float* __restrict__ mb1, const float* __restrict__ mb2,
                const float* __restrict__ mb3, const float* __restrict__ mb4,
                const _Float16* __restrict__ pwm, const _Float16* __restrict__ pw4,
                float* __restrict__ out) {
    __shared__ _Float16 act[32768];        // 128 samples x 256 features (64 KB)
    __shared__ float sArea[128], sRelH[128], sRelW[128];
    __shared__ int sCell[128];
    __shared__ float sWh[256], sWw[256];

    int t = threadIdx.x;
    int bid = blockIdx.x;
    int logical = (bid & 7) * 1024 + (bid >> 3);   // XCD-contiguous pixel strips
    int p0 = logical << 5;                          // 32 pixels per block

    if (t < 128) {
        int lp = t >> 2, rc = t & 3;
        int p = p0 + lp;
        int oh = p >> 9, ow = p & 511;
        float sh = (oh + 0.5f) * (2.0f / 512.0f) - 1.0f;
        float sw = (ow + 0.5f) * (2.0f / 512.0f) - 1.0f;
        float gh = sh + (((rc >> 1) != 0) ? (1.0f / 128.0f) : (-1.0f / 128.0f));
        float gw = sw + (((rc & 1) != 0) ? (1.0f / 128.0f) : (-1.0f / 128.0f));
        const float lim = 1.0f - 1e-6f;
        gh = fminf(fmaxf(gh, -lim), lim);
        gw = fminf(fmaxf(gw, -lim), lim);
        int iy = (int)rintf(((gh + 1.0f) * 128.0f - 1.0f) * 0.5f);  // round-half-even
        int ix = (int)rintf(((gw + 1.0f) * 128.0f - 1.0f) * 0.5f);
        iy = iy < 0 ? 0 : (iy > 127 ? 127 : iy);
        ix = ix < 0 ? 0 : (ix > 127 ? 127 : ix);
        float cy = (iy + 0.5f) * (2.0f / 128.0f) - 1.0f;
        float cx = (ix + 0.5f) * (2.0f / 128.0f) - 1.0f;
        float rh = (sh - cy) * 128.0f;
        float rw = (sw - cx) * 128.0f;
        sCell[t] = (iy << 7) + ix;
        sRelH[t] = rh; sRelW[t] = rw;
        sArea[t] = fabsf(rh * rw);
    }
    if (t < 256) {
        sWh[t] = mw0[576 * 256 + t];
        sWw[t] = mw0[577 * 256 + t];
    }
    __syncthreads();

    int wave = t >> 6, lane = t & 63, q = lane >> 4, r = lane & 15;

    // layer 1: lane-linear staging. Thread handles sample s = wave*16 + r,
    // features f = j*32 + q*8 .. +8, j = 0..7. Write chunk = wave*8 + j.
    {
        int s = (wave << 4) + r;
        float rh = sRelH[s], rw = sRelW[s];
        const float* ap = apre + ((size_t)sCell[s] << 8) + (q << 3);
        #pragma unroll
        for (int j = 0; j < 8; ++j) {
            int f0 = (j << 5) + (q << 3);
            float4v lo = *(const float4v*)(ap + (j << 5));
            float4v hi = *(const float4v*)(ap + (j << 5) + 4);
            half8 hv;
            #pragma unroll
            for (int kk = 0; kk < 4; ++kk) {
                float v = lo[kk] + rh * sWh[f0 + kk] + rw * sWw[f0 + kk];
                hv[kk] = (_Float16)fmaxf(v, 0.0f);
            }
            #pragma unroll
            for (int kk = 0; kk < 4; ++kk) {
                float v = hi[kk] + rh * sWh[f0 + 4 + kk] + rw * sWw[f0 + 4 + kk];
                hv[4 + kk] = (_Float16)fmaxf(v, 0.0f);
            }
            *(half8*)(act + ((((wave << 3) + j) * 64 + lane) << 3)) = hv;
        }
    }
    __syncthreads();

    // hidden layers: wave owns out-features [wave*32, +32) x 128 samples.
    float4v acc[2][8];
    #pragma unroll 1
    for (int l = 0; l < 3; ++l) {
        #pragma unroll
        for (int mti = 0; mti < 2; ++mti)
            #pragma unroll
            for (int nts = 0; nts < 8; ++nts)
                acc[mti][nts] = (float4v){0.f, 0.f, 0.f, 0.f};
        const _Float16* pw = pwm + l * 65536;
        for (int kc = 0; kc < 8; ++kc) {
            half8 A0 = *(const half8*)(pw + ((((wave * 2 + 0) * 8 + kc) * 64 + lane) << 3));
            half8 A1 = *(const half8*)(pw + ((((wave * 2 + 1) * 8 + kc) * 64 + lane) << 3));
            half8 Bf[4];
            #pragma unroll
            for (int nts = 0; nts < 4; ++nts)
                Bf[nts] = *(const half8*)(act + ((((nts << 3) + kc) * 64 + lane) << 3));
            #pragma unroll
            for (int nts = 0; nts < 4; ++nts) {
                acc[0][nts] = __builtin_amdgcn_mfma_f32_16x16x32_f16(A0, Bf[nts], acc[0][nts], 0, 0, 0);
                acc[1][nts] = __builtin_amdgcn_mfma_f32_16x16x32_f16(A1, Bf[nts], acc[1][nts], 0, 0, 0);
            }
            #pragma unroll
            for (int nts = 0; nts < 4; ++nts)
                Bf[nts] = *(const half8*)(act + (((((nts + 4) << 3) + kc) * 64 + lane) << 3));
            #pragma unroll
            for (int nts = 0; nts < 4; ++nts) {
                acc[0][nts + 4] = __builtin_amdgcn_mfma_f32_16x16x32_f16(A0, Bf[nts], acc[0][nts + 4], 0, 0, 0);
                acc[1][nts + 4] = __builtin_amdgcn_mfma_f32_16x16x32_f16(A1, Bf[nts], acc[1][nts + 4], 0, 0, 0);
            }
        }
        const float* mb = (l == 0) ? mb1 : ((l == 1) ? mb2 : mb3);
        __syncthreads();   // all waves done reading act
        #pragma unroll
        for (int mti = 0; mti < 2; ++mti) {
            float4v bvv = *(const float4v*)(mb + (wave << 5) + mti * 16 + (q << 2));
            #pragma unroll
            for (int nts = 0; nts < 8; ++nts) {
                int base = ((((nts << 3) + wave) * 64
                             + ((mti * 2 + (q >> 1)) << 4) + r) << 3) + ((q & 1) << 2);
                half4 hv;
                #pragma unroll
                for (int reg = 0; reg < 4; ++reg)
                    hv[reg] = (_Float16)fmaxf(acc[mti][nts][reg] + bvv[reg], 0.0f);
                *(half4*)(act + base) = hv;
            }
        }
        __syncthreads();
    }

    // final layer: wave w handles samples [w*16, w*16+16)
    {
        float4v af = {0.f, 0.f, 0.f, 0.f};
        #pragma unroll
        for (int kc = 0; kc < 8; ++kc) {
            half8 A = *(const half8*)(pw4 + ((kc * 64 + lane) << 3));
            half8 Bf = *(const half8*)(act + ((((wave << 3) + kc) * 64 + lane) << 3));
            af = __builtin_amdgcn_mfma_f32_16x16x32_f16(A, Bf, af, 0, 0, 0);
        }
        int s = (wave << 4) + r;
        int lp = s >> 2, rc = s & 3;
        float ar = sArea[(lp << 2) + (3 - rc)];    // LIIF diagonal-swapped area
        float c0 = (af[0] + mb4[0]) * ar;
        float c1 = (af[1] + mb4[1]) * ar;
        float c2 = (af[2] + mb4[2]) * ar;
        c0 += __shfl_xor(c0, 1); c1 += __shfl_xor(c1, 1); c2 += __shfl_xor(c2, 1);
        float at = ar + __shfl_xor(ar, 1);
        c0 += __shfl_xor(c0, 2); c1 += __shfl_xor(c1, 2); c2 += __shfl_xor(c2, 2);
        at += __shfl_xor(at, 2);
        if (q == 0 && rc == 0) {
            float inv = 1.0f / (at + 1e-9f);
            out[p0 + lp]          = fminf(fmaxf(c0 * inv, 0.0f), 1.0f);
            out[262144 + p0 + lp] = fminf(fmaxf(c1 * inv, 0.0f), 1.0f);
            out[524288 + p0 + lp] = fminf(fmaxf(c2 * inv, 0.0f), 1.0f);
        }
    }
}

extern "C" void kernel_launch(void* const* d_in, const int* in_sizes, int n_in,
                              void* d_out, int out_size, void* d_ws, size_t ws_size,
                              hipStream_t stream) {
    (void)in_sizes; (void)n_in; (void)out_size; (void)ws_size;
    const float* x      = (const float*)d_in[0];
    const float* head_w = (const float*)d_in[2];
    const float* head_b = (const float*)d_in[3];
    const float* rb_w   = (const float*)d_in[4];
    const float* rb_b   = (const float*)d_in[5];
    const float* tail_w = (const float*)d_in[6];
    const float* tail_b = (const float*)d_in[7];
    const float* mw0    = (const float*)d_in[8];
    const float* mb0    = (const float*)d_in[9];
    const float* mw1    = (const float*)d_in[10];
    const float* mb1    = (const float*)d_in[11];
    const float* mw2    = (const float*)d_in[12];
    const float* mb2    = (const float*)d_in[13];
    const float* mw3    = (const float*)d_in[14];
    const float* mb3    = (const float*)d_in[15];
    const float* mw4    = (const float*)d_in[16];
    const float* mb4    = (const float*)d_in[17];
    float* out = (float*)d_out;

    char* w = (char*)d_ws;
    auto take = [&](size_t n) { char* p = w; w += (n + 255) & ~(size_t)255; return p; };
    _Float16* pwc  = (_Float16*)take(33u * 36864u * 2u);
    _Float16* pw0  = (_Float16*)take(147456u * 2u);
    _Float16* pwm  = (_Float16*)take(200704u * 2u);
    float*    b0p  = (float*)take(256u * 4u);
    _Float16* h0   = (_Float16*)take((size_t)NPIX * 64u * 2u);
    _Float16* hbuf = (_Float16*)take((size_t)NPIX * 64u * 2u);
    _Float16* tbuf = (_Float16*)take((size_t)NPIX * 64u * 2u);
    _Float16* feat = (_Float16*)take((size_t)NPIX * 64u * 2u);
    float*    apre = (float*)take((size_t)NPIX * 256u * 4u);

    pack_all<<<10209, 256, 0, stream>>>(rb_w, tail_w, mw0, mw1, mw2, mw3, mw4, mb0,
                                        x, head_w, head_b, pwc, pw0, pwm, b0p, h0);

    // 4 fused 4-resblock dispatches, ping-pong hbuf/tbuf
    const _Float16* cur = h0;
    for (int p = 0; p < 4; ++p) {
        _Float16* dst = (p & 1) ? tbuf : hbuf;
        rb_quad<<<256, 512, 0, stream>>>(cur, pwc + 8 * p * 36864, rb_b + p * 512, dst);
        cur = dst;
    }
    // feat = h0 + tail(rb-chain output)
    conv_mfma_r<4, 2, false, true, false><<<512, 256, 0, stream>>>(
        cur, pwc + 32 * 36864, tail_b, h0, feat, nullptr);
    // stage A: apre[cell][256] = im2col(feat) @ mw0[:576] + b0'
    conv_mfma_r<16, 4, false, false, true><<<1024, 256, 0, stream>>>(
        feat, pw0, b0p, nullptr, nullptr, apre);

    mlp_kernel<<<8192, 512, 0, stream>>>(apre, mw0, mb1, mb2, mb3, mb4,
                                         pwm, pwm + 196608, out);
}

// Round 14
// 755.940 us; speedup vs baseline: 1.0469x; 1.0469x over previous
//
#include <hip/hip_runtime.h>
#include <hip/hip_fp16.h>

typedef __attribute__((ext_vector_type(8))) _Float16 half8;
typedef __attribute__((ext_vector_type(4))) _Float16 half4;
typedef __attribute__((ext_vector_type(4))) float float4v;

#define NPIX 16384  // 128*128

__device__ inline half8 h8zero() {
    half8 z = {(_Float16)0, (_Float16)0, (_Float16)0, (_Float16)0,
               (_Float16)0, (_Float16)0, (_Float16)0, (_Float16)0};
    return z;
}

// ---------------- all weight packing + head conv in ONE dispatch ----------------
__global__ void pack_all(const float* __restrict__ rb_w, const float* __restrict__ tail_w,
                         const float* __restrict__ mw0, const float* __restrict__ mw1,
                         const float* __restrict__ mw2, const float* __restrict__ mw3,
                         const float* __restrict__ mw4, const float* __restrict__ mb0,
                         const float* __restrict__ x, const float* __restrict__ head_w,
                         const float* __restrict__ head_b,
                         _Float16* __restrict__ pwc, _Float16* __restrict__ pw0,
                         _Float16* __restrict__ pwm, float* __restrict__ b0p,
                         _Float16* __restrict__ h0) {
    int idx = blockIdx.x * 256 + threadIdx.x;
    if (idx < 1216512) {                      // conv weights -> B-frag order
        int ci = idx / 36864;
        int e  = idx % 36864;
        int j = e & 7, ln = (e >> 3) & 63, kcnt = e >> 9;
        int kc = kcnt % 18, ntc = kcnt / 18;
        int k = kc * 32 + (ln >> 4) * 8 + j;
        int nn = ntc * 16 + (ln & 15);
        int ij = k >> 6, c = k & 63;
        const float* src = (ci < 32) ? (rb_w + ci * 36864) : tail_w;
        pwc[idx] = (_Float16)src[(nn * 64 + c) * 9 + ij];
        return;
    }
    idx -= 1216512;
    if (idx < 147456) {                       // mw0[:576] pack (N=256)
        int j = idx & 7, ln = (idx >> 3) & 63, kcnt = idx >> 9;
        int kc = kcnt % 18, ntc = kcnt / 18;
        int k = kc * 32 + (ln >> 4) * 8 + j;
        int nn = ntc * 16 + (ln & 15);
        int ij = k >> 6, c = k & 63;
        pw0[idx] = (_Float16)mw0[(c * 9 + ij) * 256 + nn];
        return;
    }
    idx -= 147456;
    if (idx < 200704) {                       // mlp hidden + padded mw4
        if (idx < 196608) {
            int l = idx / 65536;
            int e = idx % 65536;
            int j = e & 7, ln = (e >> 3) & 63, kcnt = e >> 9;
            int kc = kcnt & 7, ntc = kcnt >> 3;
            int k = kc * 32 + (ln >> 4) * 8 + j;
            int nn = ntc * 16 + (ln & 15);
            const float* w = (l == 0) ? mw1 : ((l == 1) ? mw2 : mw3);
            pwm[idx] = (_Float16)w[k * 256 + nn];
        } else {
            int e = idx - 196608;
            int j = e & 7, ln = (e >> 3) & 63, kc = e >> 9;
            int k = kc * 32 + (ln >> 4) * 8 + j;
            int nn = ln & 15;
            pwm[idx] = (nn < 3) ? (_Float16)mw4[k * 3 + nn] : (_Float16)0.0f;
        }
        return;
    }
    idx -= 200704;
    if (idx < 256) {
        b0p[idx] = mb0[idx] + 0.5f * (mw0[578 * 256 + idx] + mw0[579 * 256 + idx]);
        return;
    }
    idx -= 256;
    if (idx < NPIX * 64) {                    // head conv (Cin=3, direct fp32)
        int o = idx & 63, p = idx >> 6;
        int py = p >> 7, px = p & 127;
        float acc = head_b[o];
        #pragma unroll
        for (int c = 0; c < 3; ++c)
            #pragma unroll
            for (int i = 0; i < 3; ++i)
                #pragma unroll
                for (int jj = 0; jj < 3; ++jj) {
                    int y = py + i - 1, xx = px + jj - 1;
                    if (y >= 0 && y < 128 && xx >= 0 && xx < 128)
                        acc += x[c * 16384 + y * 128 + xx]
                             * head_w[((o * 3 + c) * 3 + i) * 3 + jj];
                }
        h0[idx] = (_Float16)acc;
    }
}

// ---------------- fused resblock kernels ----------------
#define LDS_STRIDE 72

// RES: 0 = relu -> LDS dst; 1 = +residual IN(+ROFF), in-place into IN;
//      2 = +residual IN(+ROFF), global out; 3 = +residual GLOBAL resg, global out.
// INW = IN buffer pixel width (16 for rb_pair halo-4, 18 for rb_tail halo-5).
template <int DH, int DW, int SW, int SOFF, int RES, int ROFF, int INW>
__device__ __forceinline__ void conv_stage(
    const _Float16* __restrict__ src, _Float16* __restrict__ dst,
    _Float16* __restrict__ INb, const _Float16* __restrict__ resg,
    const _Float16* __restrict__ pw, const float* __restrict__ bias,
    int q, int r, int nb, int gy0, int gx0, _Float16* __restrict__ gout)
{
    half8 B[18];
    #pragma unroll
    for (int kc = 0; kc < 18; ++kc)
        B[kc] = *(const half8*)(pw + ((((nb >> 4) * 18 + kc) * 64 + (q << 4) + r) << 3));
    float bv = bias[nb + r];
    constexpr int NPXc = DH * DW;
    constexpr int NT = (NPXc + 15) >> 4;
    #pragma unroll 1
    for (int tl = 0; tl < NT; ++tl) {
        int pa = tl * 16 + r;
        int ca = pa < NPXc ? pa : NPXc - 1;
        int my = ca / DW, mx = ca % DW;
        float4v acc = {0.f, 0.f, 0.f, 0.f};
        #pragma unroll
        for (int kc = 0; kc < 18; ++kc) {
            int ij = kc >> 1;
            int di = ij / 3 - 1;
            int dj = ij % 3 - 1;
            int cb = ((kc & 1) << 5) + (q << 3);
            int sp = (my + 1 + di + SOFF) * SW + (mx + 1 + dj + SOFF);
            half8 a = *(const half8*)(src + sp * LDS_STRIDE + cb);
            acc = __builtin_amdgcn_mfma_f32_16x16x32_f16(a, B[kc], acc, 0, 0, 0);
        }
        #pragma unroll
        for (int reg = 0; reg < 4; ++reg) {
            int pc = tl * 16 + (q << 2) + reg;
            if (pc >= NPXc) continue;
            int dy = pc / DW, dx = pc % DW;
            int gy = gy0 + dy, gx = gx0 + dx;
            bool valid = (gy >= 0 && gy < 128 && gx >= 0 && gx < 128);
            if (RES == 0) {
                float v = fmaxf(acc[reg] + bv, 0.f);
                dst[pc * LDS_STRIDE + nb + r] = valid ? (_Float16)v : (_Float16)0.0f;
            } else if (RES == 1) {
                int sl = ((dy + ROFF) * INW + dx + ROFF) * LDS_STRIDE + nb + r;
                float v = acc[reg] + bv + (float)INb[sl];
                INb[sl] = valid ? (_Float16)v : (_Float16)0.0f;
            } else if (RES == 2) {
                int sl = ((dy + ROFF) * INW + dx + ROFF) * LDS_STRIDE + nb + r;
                float v = acc[reg] + bv + (float)INb[sl];
                gout[(((gy << 7) + gx) << 6) + nb + r] = (_Float16)v;
            } else {
                float v = acc[reg] + bv + (float)resg[(((gy << 7) + gx) << 6) + nb + r];
                gout[(((gy << 7) + gx) << 6) + nb + r] = (_Float16)v;
            }
        }
    }
}

__global__ __launch_bounds__(256, 3)
void rb_pair(const _Float16* __restrict__ img, const _Float16* __restrict__ pw,
             const float* __restrict__ bias, _Float16* __restrict__ out) {
    __shared__ _Float16 IN[192 * LDS_STRIDE];    // 12x16 px, 27.6 KB
    __shared__ _Float16 MID[140 * LDS_STRIDE];   // up to 10x14 px, 20.2 KB
    int t = threadIdx.x;
    int wave = t >> 6, lane = t & 63, q = lane >> 4, r = lane & 15;
    int tr = blockIdx.x >> 4, tc = blockIdx.x & 15;
    int ty0 = tr << 2, tx0 = tc << 3;
    int nb = wave << 4;

    #pragma unroll
    for (int i = 0; i < 6; ++i) {
        int idx = t + i * 256;                   // 1536 = 192 px * 8 chunks
        int px = idx >> 3, c = idx & 7;
        int iy = px >> 4, ix = px & 15;
        int gy = ty0 - 4 + iy, gx = tx0 - 4 + ix;
        half8 v = h8zero();
        if (gy >= 0 && gy < 128 && gx >= 0 && gx < 128)
            v = *(const half8*)(img + (((gy << 7) + gx) << 6) + (c << 3));
        *(half8*)(IN + px * LDS_STRIDE + (c << 3)) = v;
    }
    __syncthreads();

    conv_stage<10, 14, 16, 0, 0, 0, 16>(IN, MID, IN, nullptr, pw, bias, q, r, nb,
                                        ty0 - 3, tx0 - 3, nullptr);
    __syncthreads();
    conv_stage<8, 12, 14, 0, 1, 2, 16>(MID, nullptr, IN, nullptr, pw + 36864, bias + 64,
                                       q, r, nb, ty0 - 2, tx0 - 2, nullptr);
    __syncthreads();
    conv_stage<6, 10, 16, 2, 0, 0, 16>(IN, MID, IN, nullptr, pw + 2 * 36864, bias + 128,
                                       q, r, nb, ty0 - 1, tx0 - 1, nullptr);
    __syncthreads();
    conv_stage<4, 8, 10, 0, 2, 4, 16>(MID, nullptr, IN, nullptr, pw + 3 * 36864, bias + 192,
                                      q, r, nb, ty0, tx0, out);
}

// last resblock pair + tail conv fused (halo 5).
// Stages: c1 12x16 -> c2 10x14 (res IN+2) -> c3 8x12 -> c4 6x10 (res IN+4, rb2out
// kept in LDS, OOB-zeroed) -> tail 4x8 + h0 residual (global) -> feat.
// Tail weights sit contiguously at pw + 4*36864 (pwc layout: convs 28..31, tail).
__global__ __launch_bounds__(256, 2)
void rb_tail(const _Float16* __restrict__ img, const _Float16* __restrict__ h0res,
             const _Float16* __restrict__ pw, const float* __restrict__ bias,
             const float* __restrict__ tail_b, _Float16* __restrict__ out) {
    __shared__ _Float16 IN[252 * LDS_STRIDE];    // 14x18 px, 36.3 KB
    __shared__ _Float16 MID[192 * LDS_STRIDE];   // up to 12x16 px, 27.6 KB
    int t = threadIdx.x;
    int wave = t >> 6, lane = t & 63, q = lane >> 4, r = lane & 15;
    int tr = blockIdx.x >> 4, tc = blockIdx.x & 15;
    int ty0 = tr << 2, tx0 = tc << 3;
    int nb = wave << 4;

    // stage IN (halo 5): rows ty0-5..ty0+8, cols tx0-5..tx0+12 (14x18)
    #pragma unroll
    for (int i = 0; i < 8; ++i) {
        int idx = t + i * 256;                   // 2016 = 252 px * 8 chunks
        if (idx < 2016) {
            int px = idx >> 3, c = idx & 7;
            int iy = px / 18, ix = px % 18;
            int gy = ty0 - 5 + iy, gx = tx0 - 5 + ix;
            half8 v = h8zero();
            if (gy >= 0 && gy < 128 && gx >= 0 && gx < 128)
                v = *(const half8*)(img + (((gy << 7) + gx) << 6) + (c << 3));
            *(half8*)(IN + px * LDS_STRIDE + (c << 3)) = v;
        }
    }
    __syncthreads();

    conv_stage<12, 16, 18, 0, 0, 0, 18>(IN, MID, IN, nullptr, pw, bias, q, r, nb,
                                        ty0 - 4, tx0 - 4, nullptr);
    __syncthreads();
    conv_stage<10, 14, 16, 0, 1, 2, 18>(MID, nullptr, IN, nullptr, pw + 36864, bias + 64,
                                        q, r, nb, ty0 - 3, tx0 - 3, nullptr);
    __syncthreads();
    conv_stage<8, 12, 18, 2, 0, 0, 18>(IN, MID, IN, nullptr, pw + 2 * 36864, bias + 128,
                                       q, r, nb, ty0 - 2, tx0 - 2, nullptr);
    __syncthreads();
    conv_stage<6, 10, 12, 0, 1, 4, 18>(MID, nullptr, IN, nullptr, pw + 3 * 36864, bias + 192,
                                       q, r, nb, ty0 - 1, tx0 - 1, nullptr);
    __syncthreads();
    // tail: feat = h0 + conv(rb2out);  rb2out lives at IN(+4,+4)
    conv_stage<4, 8, 18, 4, 3, 0, 18>(IN, nullptr, IN, h0res, pw + 4 * 36864, tail_b,
                                      q, r, nb, ty0, tx0, out);
}

// ---------------- unfused conv (stage-A) ----------
template <int NTOT, int MTPER, bool RELU, bool RES, bool F32OUT>
__global__ __launch_bounds__(256, 2)
void conv_mfma_r(const _Float16* __restrict__ img, const _Float16* __restrict__ pw,
                 const float* __restrict__ bias, const _Float16* res,
                 _Float16* outh, float* outf) {
    int wave = threadIdx.x >> 6, lane = threadIdx.x & 63;
    int q = lane >> 4, r = lane & 15;
    int nt, mt0;
    if constexpr (NTOT == 4) {
        nt = wave;
        mt0 = blockIdx.x * MTPER;
    } else {
        nt = (blockIdx.x & 3) * 4 + wave;
        mt0 = (blockIdx.x >> 2) * MTPER;
    }
    half8 B[18];
    #pragma unroll
    for (int kc = 0; kc < 18; ++kc)
        B[kc] = *(const half8*)(pw + (((nt * 18 + kc) * 64 + lane) << 3));
    int n = nt * 16 + r;
    float bv = bias[n];
    #pragma unroll
    for (int mi = 0; mi < MTPER; ++mi) {
        int mt = mt0 + mi;
        int p0 = mt * 16;
        int py = p0 >> 7;
        int pxl = (p0 & 127) + r;
        float4v acc = {0.f, 0.f, 0.f, 0.f};
        #pragma unroll
        for (int kc = 0; kc < 18; ++kc) {
            int ij = kc >> 1;
            int di = ij / 3 - 1;
            int dj = ij % 3 - 1;
            int cb = ((kc & 1) << 5) + (q << 3);
            int yy = py + di, xx = pxl + dj;
            half8 a = h8zero();
            if (yy >= 0 && yy < 128 && xx >= 0 && xx < 128)
                a = *(const half8*)(img + (((yy << 7) + xx) << 6) + cb);
            acc = __builtin_amdgcn_mfma_f32_16x16x32_f16(a, B[kc], acc, 0, 0, 0);
        }
        #pragma unroll
        for (int reg = 0; reg < 4; ++reg) {
            int p = p0 + (q << 2) + reg;
            float v = acc[reg] + bv;
            if (RES) v += (float)res[p * (NTOT * 16) + n];
            if (RELU) v = fmaxf(v, 0.f);
            if (F32OUT) outf[p * (NTOT * 16) + n] = v;
            else        outh[p * (NTOT * 16) + n] = (_Float16)v;
        }
    }
}

// ---------------- fused LIIF MLP + ensembling (32 px, 8-wave transposed) --------
// Block: 512 thr (8 waves) = 32 output pixels = 128 samples. (R12, 432 us)
__global__ __launch_bounds__(512, 4)
void mlp_kernel(const float* __restrict__ apre, const float* __restrict__ mw0,
                const float* __restrict__ mb1, const float* __restrict__ mb2,
                const float* __restrict__ mb3, const float* __restrict__ mb4,
                const _Float16* __restrict__ pwm, const _Float16* __restrict__ pw4,
                float* __restrict__ out) {
    __shared__ _Float16 act[32768];        // 128 samples x 256 features (64 KB)
    __shared__ float sArea[128], sRelH[128], sRelW[128];
    __shared__ int sCell[128];
    __shared__ float sWh[256], sWw[256];

    int t = threadIdx.x;
    int bid = blockIdx.x;
    int logical = (bid & 7) * 1024 + (bid >> 3);   // XCD-contiguous pixel strips
    int p0 = logical << 5;                          // 32 pixels per block

    if (t < 128) {
        int lp = t >> 2, rc = t & 3;
        int p = p0 + lp;
        int oh = p >> 9, ow = p & 511;
        float sh = (oh + 0.5f) * (2.0f / 512.0f) - 1.0f;
        float sw = (ow + 0.5f) * (2.0f / 512.0f) - 1.0f;
        float gh = sh + (((rc >> 1) != 0) ? (1.0f / 128.0f) : (-1.0f / 128.0f));
        float gw = sw + (((rc & 1) != 0) ? (1.0f / 128.0f) : (-1.0f / 128.0f));
        const float lim = 1.0f - 1e-6f;
        gh = fminf(fmaxf(gh, -lim), lim);
        gw = fminf(fmaxf(gw, -lim), lim);
        int iy = (int)rintf(((gh + 1.0f) * 128.0f - 1.0f) * 0.5f);  // round-half-even
        int ix = (int)rintf(((gw + 1.0f) * 128.0f - 1.0f) * 0.5f);
        iy = iy < 0 ? 0 : (iy > 127 ? 127 : iy);
        ix = ix < 0 ? 0 : (ix > 127 ? 127 : ix);
        float cy = (iy + 0.5f) * (2.0f / 128.0f) - 1.0f;
        float cx = (ix + 0.5f) * (2.0f / 128.0f) - 1.0f;
        float rh = (sh - cy) * 128.0f;
        float rw = (sw - cx) * 128.0f;
        sCell[t] = (iy << 7) + ix;
        sRelH[t] = rh; sRelW[t] = rw;
        sArea[t] = fabsf(rh * rw);
    }
    if (t < 256) {
        sWh[t] = mw0[576 * 256 + t];
        sWw[t] = mw0[577 * 256 + t];
    }
    __syncthreads();

    int wave = t >> 6, lane = t & 63, q = lane >> 4, r = lane & 15;

    // layer 1: lane-linear staging. Thread handles sample s = wave*16 + r,
    // features f = j*32 + q*8 .. +8, j = 0..7. Write chunk = wave*8 + j.
    {
        int s = (wave << 4) + r;
        float rh = sRelH[s], rw = sRelW[s];
        const float* ap = apre + ((size_t)sCell[s] << 8) + (q << 3);
        #pragma unroll
        for (int j = 0; j < 8; ++j) {
            int f0 = (j << 5) + (q << 3);
            float4v lo = *(const float4v*)(ap + (j << 5));
            float4v hi = *(const float4v*)(ap + (j << 5) + 4);
            half8 hv;
            #pragma unroll
            for (int kk = 0; kk < 4; ++kk) {
                float v = lo[kk] + rh * sWh[f0 + kk] + rw * sWw[f0 + kk];
                hv[kk] = (_Float16)fmaxf(v, 0.0f);
            }
            #pragma unroll
            for (int kk = 0; kk < 4; ++kk) {
                float v = hi[kk] + rh * sWh[f0 + 4 + kk] + rw * sWw[f0 + 4 + kk];
                hv[4 + kk] = (_Float16)fmaxf(v, 0.0f);
            }
            *(half8*)(act + ((((wave << 3) + j) * 64 + lane) << 3)) = hv;
        }
    }
    __syncthreads();

    // hidden layers: wave owns out-features [wave*32, +32) x 128 samples.
    float4v acc[2][8];
    #pragma unroll 1
    for (int l = 0; l < 3; ++l) {
        #pragma unroll
        for (int mti = 0; mti < 2; ++mti)
            #pragma unroll
            for (int nts = 0; nts < 8; ++nts)
                acc[mti][nts] = (float4v){0.f, 0.f, 0.f, 0.f};
        const _Float16* pw = pwm + l * 65536;
        for (int kc = 0; kc < 8; ++kc) {
            half8 A0 = *(const half8*)(pw + ((((wave * 2 + 0) * 8 + kc) * 64 + lane) << 3));
            half8 A1 = *(const half8*)(pw + ((((wave * 2 + 1) * 8 + kc) * 64 + lane) << 3));
            half8 Bf[4];
            #pragma unroll
            for (int nts = 0; nts < 4; ++nts)
                Bf[nts] = *(const half8*)(act + ((((nts << 3) + kc) * 64 + lane) << 3));
            #pragma unroll
            for (int nts = 0; nts < 4; ++nts) {
                acc[0][nts] = __builtin_amdgcn_mfma_f32_16x16x32_f16(A0, Bf[nts], acc[0][nts], 0, 0, 0);
                acc[1][nts] = __builtin_amdgcn_mfma_f32_16x16x32_f16(A1, Bf[nts], acc[1][nts], 0, 0, 0);
            }
            #pragma unroll
            for (int nts = 0; nts < 4; ++nts)
                Bf[nts] = *(const half8*)(act + (((((nts + 4) << 3) + kc) * 64 + lane) << 3));
            #pragma unroll
            for (int nts = 0; nts < 4; ++nts) {
                acc[0][nts + 4] = __builtin_amdgcn_mfma_f32_16x16x32_f16(A0, Bf[nts], acc[0][nts + 4], 0, 0, 0);
                acc[1][nts + 4] = __builtin_amdgcn_mfma_f32_16x16x32_f16(A1, Bf[nts], acc[1][nts + 4], 0, 0, 0);
            }
        }
        const float* mb = (l == 0) ? mb1 : ((l == 1) ? mb2 : mb3);
        __syncthreads();   // all waves done reading act
        #pragma unroll
        for (int mti = 0; mti < 2; ++mti) {
            float4v bvv = *(const float4v*)(mb + (wave << 5) + mti * 16 + (q << 2));
            #pragma unroll
            for (int nts = 0; nts < 8; ++nts) {
                int base = ((((nts << 3) + wave) * 64
                             + ((mti * 2 + (q >> 1)) << 4) + r) << 3) + ((q & 1) << 2);
                half4 hv;
                #pragma unroll
                for (int reg = 0; reg < 4; ++reg)
                    hv[reg] = (_Float16)fmaxf(acc[mti][nts][reg] + bvv[reg], 0.0f);
                *(half4*)(act + base) = hv;
            }
        }
        __syncthreads();
    }

    // final layer: wave w handles samples [w*16, w*16+16)
    {
        float4v af = {0.f, 0.f, 0.f, 0.f};
        #pragma unroll
        for (int kc = 0; kc < 8; ++kc) {
            half8 A = *(const half8*)(pw4 + ((kc * 64 + lane) << 3));
            half8 Bf = *(const half8*)(act + ((((wave << 3) + kc) * 64 + lane) << 3));
            af = __builtin_amdgcn_mfma_f32_16x16x32_f16(A, Bf, af, 0, 0, 0);
        }
        int s = (wave << 4) + r;
        int lp = s >> 2, rc = s & 3;
        float ar = sArea[(lp << 2) + (3 - rc)];    // LIIF diagonal-swapped area
        float c0 = (af[0] + mb4[0]) * ar;
        float c1 = (af[1] + mb4[1]) * ar;
        float c2 = (af[2] + mb4[2]) * ar;
        c0 += __shfl_xor(c0, 1); c1 += __shfl_xor(c1, 1); c2 += __shfl_xor(c2, 1);
        float at = ar + __shfl_xor(ar, 1);
        c0 += __shfl_xor(c0, 2); c1 += __shfl_xor(c1, 2); c2 += __shfl_xor(c2, 2);
        at += __shfl_xor(at, 2);
        if (q == 0 && rc == 0) {
            float inv = 1.0f / (at + 1e-9f);
            out[p0 + lp]          = fminf(fmaxf(c0 * inv, 0.0f), 1.0f);
            out[262144 + p0 + lp] = fminf(fmaxf(c1 * inv, 0.0f), 1.0f);
            out[524288 + p0 + lp] = fminf(fmaxf(c2 * inv, 0.0f), 1.0f);
        }
    }
}

extern "C" void kernel_launch(void* const* d_in, const int* in_sizes, int n_in,
                              void* d_out, int out_size, void* d_ws, size_t ws_size,
                              hipStream_t stream) {
    (void)in_sizes; (void)n_in; (void)out_size; (void)ws_size;
    const float* x      = (const float*)d_in[0];
    const float* head_w = (const float*)d_in[2];
    const float* head_b = (const float*)d_in[3];
    const float* rb_w   = (const float*)d_in[4];
    const float* rb_b   = (const float*)d_in[5];
    const float* tail_w = (const float*)d_in[6];
    const float* tail_b = (const float*)d_in[7];
    const float* mw0    = (const float*)d_in[8];
    const float* mb0    = (const float*)d_in[9];
    const float* mw1    = (const float*)d_in[10];
    const float* mb1    = (const float*)d_in[11];
    const float* mw2    = (const float*)d_in[12];
    const float* mb2    = (const float*)d_in[13];
    const float* mw3    = (const float*)d_in[14];
    const float* mb3    = (const float*)d_in[15];
    const float* mw4    = (const float*)d_in[16];
    const float* mb4    = (const float*)d_in[17];
    float* out = (float*)d_out;

    char* w = (char*)d_ws;
    auto take = [&](size_t n) { char* p = w; w += (n + 255) & ~(size_t)255; return p; };
    _Float16* pwc  = (_Float16*)take(33u * 36864u * 2u);
    _Float16* pw0  = (_Float16*)take(147456u * 2u);
    _Float16* pwm  = (_Float16*)take(200704u * 2u);
    float*    b0p  = (float*)take(256u * 4u);
    _Float16* h0   = (_Float16*)take((size_t)NPIX * 64u * 2u);
    _Float16* hbuf = (_Float16*)take((size_t)NPIX * 64u * 2u);
    _Float16* tbuf = (_Float16*)take((size_t)NPIX * 64u * 2u);
    _Float16* feat = (_Float16*)take((size_t)NPIX * 64u * 2u);
    float*    apre = (float*)take((size_t)NPIX * 256u * 4u);

    pack_all<<<10209, 256, 0, stream>>>(rb_w, tail_w, mw0, mw1, mw2, mw3, mw4, mb0,
                                        x, head_w, head_b, pwc, pw0, pwm, b0p, h0);

    // 7 fused 2-resblock dispatches + 1 fused last-pair+tail dispatch
    const _Float16* cur = h0;
    for (int p = 0; p < 7; ++p) {
        _Float16* dst = (p & 1) ? tbuf : hbuf;
        rb_pair<<<512, 256, 0, stream>>>(cur, pwc + 4 * p * 36864, rb_b + p * 256, dst);
        cur = dst;
    }
    // pair 7 + tail + h0 residual -> feat  (weights 28..31 + tail contiguous)
    rb_tail<<<512, 256, 0, stream>>>(cur, h0, pwc + 28 * 36864, rb_b + 7 * 256,
                                     tail_b, feat);
    // stage A: apre[cell][256] = im2col(feat) @ mw0[:576] + b0'
    conv_mfma_r<16, 4, false, false, true><<<1024, 256, 0, stream>>>(
        feat, pw0, b0p, nullptr, nullptr, apre);

    mlp_kernel<<<8192, 512, 0, stream>>>(apre, mw0, mb1, mb2, mb3, mb4,
                                         pwm, pwm + 196608, out);
}